// Round 3
// baseline (90.990 us; speedup 1.0000x reference)
//
#include <hip/hip_runtime.h>
#include <math.h>

// x [B=1024, S=256, E=4] fp32. R10: occupancy push on the R9 MFMA structure.
// Grid = 2*B blocks; block handles 128 queries (2 row-tiles/wave), all 256 keys.
//  - scores: mfma_f32_16x16x32_f16(K-frag, Q-frag, -mhat), fp16 hi/lo split
//    => (kh+kl)(qh+ql) exact product of split values (~2^-21 rel).
//  - P.V: bf16 MFMA (range: bf16 subnormals to 2^-133, so the loose mhat
//    bound can never underflow the whole row => l>0, no NaN).
//    P split Ph+Pl (RTZ perms), V split Vh+Vl (RNE).
//  - LDS diet 35.3->15.6 KB: vcomb[8][264] replaces the two 16-row tables;
//    ones-column / zero-padding synthesized with cndmask (garbage loads land
//    only in never-stored D columns; MFMA columns are independent).
//  - launch_bounds(256,5): 102-VGPR cap, 5 waves/SIMD (was 4).
constexpr int S  = 256;
constexpr int E  = 4;
constexpr int H1 = 8;
constexpr int H2 = 4;

typedef __attribute__((ext_vector_type(8))) _Float16 half8;
typedef __attribute__((ext_vector_type(8))) short    bf16x8;
typedef __attribute__((ext_vector_type(4))) float    f32x4;
typedef __attribute__((ext_vector_type(4))) int      i32x4;

__device__ __forceinline__ float fast_tanh(float x) {
    const float z = __builtin_amdgcn_exp2f(x * 2.88539008f);  // e^(2x)
    return 1.f - 2.f * __builtin_amdgcn_rcpf(z + 1.f);        // inf-safe
}

// fp32 -> (hi fp16, lo fp16) split, hi RNE, residual captured in lo.
__device__ __forceinline__ void split16(float x, unsigned short& hi, unsigned short& lo) {
    _Float16 h = (_Float16)x;
    float r = x - (float)h;
    _Float16 l = (_Float16)r;
    hi = __builtin_bit_cast(unsigned short, h);
    lo = __builtin_bit_cast(unsigned short, l);
}

__device__ __forceinline__ unsigned short bf16_rne(float x) {
    unsigned u = __builtin_bit_cast(unsigned, x);
    u = (u + 0x7FFFu + ((u >> 16) & 1u)) >> 16;
    return (unsigned short)u;
}
__device__ __forceinline__ float bf16_as_f32(unsigned short h) {
    return __builtin_bit_cast(float, (unsigned)h << 16);
}

// pack: low16 = bf16_rtz(a), high16 = bf16_rtz(b)  (one v_perm_b32)
__device__ __forceinline__ unsigned pk_bf16(float a, float b) {
    return __builtin_amdgcn_perm(__builtin_bit_cast(unsigned, b),
                                 __builtin_bit_cast(unsigned, a), 0x07060302u);
}
__device__ __forceinline__ float hi_part(float a) {  // bf16_rtz(a) as f32
    return __builtin_bit_cast(float, __builtin_bit_cast(unsigned, a) & 0xFFFF0000u);
}

__device__ __forceinline__ half8 frag(int a, int b, int c, int d) {
    i32x4 t = {a, b, c, d};
    return __builtin_bit_cast(half8, t);
}
__device__ __forceinline__ bf16x8 bfrag(int a, int b, int c, int d) {
    i32x4 t = {a, b, c, d};
    return __builtin_bit_cast(bf16x8, t);
}
__device__ __forceinline__ f32x4 mfma_f16(half8 a, half8 b, f32x4 c) {
    return __builtin_amdgcn_mfma_f32_16x16x32_f16(a, b, c, 0, 0, 0);
}
__device__ __forceinline__ f32x4 mfma_bf16(bf16x8 a, bf16x8 b, f32x4 c) {
    return __builtin_amdgcn_mfma_f32_16x16x32_bf16(a, b, c, 0, 0, 0);
}

__global__ __launch_bounds__(256, 5) void attn_mlp_kernel(
    const float* __restrict__ x,
    const float* __restrict__ Wq, const float* __restrict__ Wk, const float* __restrict__ Wv,
    const float* __restrict__ W1, const float* __restrict__ b1,
    const float* __restrict__ W2, const float* __restrict__ b2,
    const float* __restrict__ W3, const float* __restrict__ b3,
    float* __restrict__ out)
{
    const int blk   = blockIdx.x;
    const int b     = blk >> 1;
    const int qbase = (blk & 1) << 7;     // this block's 128 queries
    const int tid  = threadIdx.x;
    const int w    = tid >> 6;
    const int lane = tid & 63;
    const int g    = lane >> 4;
    const int c15  = lane & 15;

    __shared__ i32x4 qrec[S];                             // fp16 [qh01,qh23,ql01,ql23]
    __shared__ i32x4 krec[S];                             // fp16 [kh01,kh23,kl01,kl23]
    __shared__ __align__(16) unsigned short vcomb[8][264]; // bf16 rows 0-3 vh, 4-7 vl
    __shared__ float mh_lds[S];                           // negated per-row score bound
    __shared__ float accb[128][5];                        // [v0..v3, l]
    __shared__ float kmax_lds[4];

    // ---- Phase 0: q/k/v for row tid; splits into LDS ----
    const float4 xr = *reinterpret_cast<const float4*>(x + ((size_t)b * S + tid) * E);
    const float xv[E] = {xr.x, xr.y, xr.z, xr.w};
    float qq = 0.f, kk = 0.f;
    {
        float q[E], k[E], v[E];
        #pragma unroll
        for (int e = 0; e < E; ++e) {
            float aq = 0.f, ak = 0.f, av = 0.f;
            #pragma unroll
            for (int i = 0; i < E; ++i) {
                aq = fmaf(xv[i], Wq[i * E + e], aq);
                ak = fmaf(xv[i], Wk[i * E + e], ak);
                av = fmaf(xv[i], Wv[i * E + e], av);
            }
            q[e] = aq * 0.72134752f;  // fold 1/sqrt(E), log2(e): exp2 domain
            k[e] = ak;
            v[e] = av;
            qq = fmaf(q[e], q[e], qq);
            kk = fmaf(ak, ak, kk);
        }
        unsigned short qh[4], ql[4], kh[4], kl[4];
        #pragma unroll
        for (int e = 0; e < E; ++e) {
            split16(q[e], qh[e], ql[e]);
            split16(k[e], kh[e], kl[e]);
        }
        qrec[tid] = (i32x4){ (int)(qh[0] | (qh[1] << 16)), (int)(qh[2] | (qh[3] << 16)),
                             (int)(ql[0] | (ql[1] << 16)), (int)(ql[2] | (ql[3] << 16)) };
        krec[tid] = (i32x4){ (int)(kh[0] | (kh[1] << 16)), (int)(kh[2] | (kh[3] << 16)),
                             (int)(kl[0] | (kl[1] << 16)), (int)(kl[2] | (kl[3] << 16)) };
        #pragma unroll
        for (int e = 0; e < E; ++e) {
            const unsigned short vh = bf16_rne(v[e]);
            const unsigned short vl = bf16_rne(v[e] - bf16_as_f32(vh));
            vcomb[e][tid]     = vh;
            vcomb[4 + e][tid] = vl;
        }
        #pragma unroll
        for (int off = 32; off > 0; off >>= 1)
            kk = fmaxf(kk, __shfl_xor(kk, off));
        if (lane == 0) kmax_lds[w] = kk;
    }
    __syncthreads();
    const float kmax2 = fmaxf(fmaxf(kmax_lds[0], kmax_lds[1]),
                              fmaxf(kmax_lds[2], kmax_lds[3]));
    mh_lds[tid] = -sqrtf(qq * kmax2);   // >= every score (exp2 domain), negated
    __syncthreads();

    // ---- hoist: wave w owns queries qbase+32w .. +31 (2 row-tiles) ----
    half8 Bq[2];
    float negmh[2];
    f32x4 acc[2];
    #pragma unroll
    for (int rt = 0; rt < 2; ++rt) {
        const int s = qbase + 32 * w + 16 * rt + c15;
        i32x4 u = qrec[s];
        int h0 = (g == 0) ? u[0] : u[2];
        int h1 = (g == 0) ? u[1] : u[3];
        if (g >= 2) { h0 = 0; h1 = 0; }
        Bq[rt] = frag(h0, h1, h0, h1);            // g0:[qh,qh] g1:[ql,ql]
        negmh[rt] = mh_lds[s];
        acc[rt] = (f32x4){0.f, 0.f, 0.f, 0.f};
    }

    const bool is4 = (c15 == 4);
    const bool lt4 = (c15 < 4);
    const unsigned ONES2 = 0x3F803F80u;           // two bf16 1.0 (l column)
    const int vrh = (c15 & 7);                    // Bvh row (garbage cols ignored)
    const int vrl = 4 + (c15 & 3);                // Bvl row

    // ---- main loop: 8 chunks x 32 keys, no barriers ----
    #pragma unroll 1
    for (int ch = 0; ch < 8; ++ch) {
        const int kb = ch * 32;
        i32x4 k0 = krec[kb + c15];                // key row (tile0)
        i32x4 k1 = krec[kb + 16 + c15];           // tile1
        if (g >= 2) { k0 = (i32x4){0,0,0,0}; k1 = (i32x4){0,0,0,0}; }
        const half8 Ak0 = __builtin_bit_cast(half8, k0);   // g0/g1: [kh,kl]
        const half8 Ak1 = __builtin_bit_cast(half8, k1);

        const int vi = kb + 4 * g;                // this lane's 4 keys per tile
        const uint2 h0 = *(const uint2*)&vcomb[vrh][vi];
        const uint2 h1 = *(const uint2*)&vcomb[vrh][vi + 16];
        const uint2 l0 = *(const uint2*)&vcomb[vrl][vi];
        const uint2 l1 = *(const uint2*)&vcomb[vrl][vi + 16];
        const unsigned hx0 = is4 ? ONES2 : h0.x, hy0 = is4 ? ONES2 : h0.y;
        const unsigned hx1 = is4 ? ONES2 : h1.x, hy1 = is4 ? ONES2 : h1.y;
        const unsigned lx0 = lt4 ? l0.x : 0u,    ly0 = lt4 ? l0.y : 0u;
        const unsigned lx1 = lt4 ? l1.x : 0u,    ly1 = lt4 ? l1.y : 0u;
        const bf16x8 Bvh0 = bfrag((int)hx0, (int)hy0, (int)hx0, (int)hy0); // [Vh,Vh] t0
        const bf16x8 Bvh1 = bfrag((int)hx1, (int)hy1, (int)hx1, (int)hy1); // [Vh,Vh] t1
        const bf16x8 Bvl  = bfrag((int)lx0, (int)ly0, (int)lx1, (int)ly1); // [Vl t0,Vl t1]

        #pragma unroll
        for (int rt = 0; rt < 2; ++rt) {
            const f32x4 cm = {negmh[rt], negmh[rt], negmh[rt], negmh[rt]};
            const f32x4 c0 = mfma_f16(Ak0, Bq[rt], cm);   // S^T - mhat, keys kb+4g+i
            const f32x4 c1 = mfma_f16(Ak1, Bq[rt], cm);   // keys kb+16+4g+i
            const float p0 = __builtin_amdgcn_exp2f(c0[0]);
            const float p1 = __builtin_amdgcn_exp2f(c0[1]);
            const float p2 = __builtin_amdgcn_exp2f(c0[2]);
            const float p3 = __builtin_amdgcn_exp2f(c0[3]);
            const float p4 = __builtin_amdgcn_exp2f(c1[0]);
            const float p5 = __builtin_amdgcn_exp2f(c1[1]);
            const float p6 = __builtin_amdgcn_exp2f(c1[2]);
            const float p7 = __builtin_amdgcn_exp2f(c1[3]);
            // bf16 hi/lo split of P (RTZ): hi = v_perm pack, lo = residual pack
            const unsigned hi01 = pk_bf16(p0, p1), hi23 = pk_bf16(p2, p3);
            const unsigned hi45 = pk_bf16(p4, p5), hi67 = pk_bf16(p6, p7);
            const unsigned lo01 = pk_bf16(p0 - hi_part(p0), p1 - hi_part(p1));
            const unsigned lo23 = pk_bf16(p2 - hi_part(p2), p3 - hi_part(p3));
            const unsigned lo45 = pk_bf16(p4 - hi_part(p4), p5 - hi_part(p5));
            const unsigned lo67 = pk_bf16(p6 - hi_part(p6), p7 - hi_part(p7));
            const bf16x8 A10 = bfrag((int)hi01, (int)hi23, (int)lo01, (int)lo23);
            const bf16x8 A11 = bfrag((int)hi45, (int)hi67, (int)lo45, (int)lo67);
            const bf16x8 A2  = bfrag((int)hi01, (int)hi23, (int)hi45, (int)hi67);
            acc[rt] = mfma_bf16(A10, Bvh0, acc[rt]);   // (Ph+Pl).Vh tile0 (+ l)
            acc[rt] = mfma_bf16(A11, Bvh1, acc[rt]);   // (Ph+Pl).Vh tile1 (+ l)
            acc[rt] = mfma_bf16(A2,  Bvl,  acc[rt]);   // Ph.Vl both tiles
        }
    }

    // ---- epilogue: C layout row=4g+i (query), col=c15 (v0..v3,l) ----
    #pragma unroll
    for (int rt = 0; rt < 2; ++rt) {
        if (c15 < 5) {
            const int row = 32 * w + 16 * rt + 4 * g;   // 0..127 within block
            #pragma unroll
            for (int i = 0; i < 4; ++i) accb[row + i][c15] = acc[rt][i];
        }
    }
    __syncthreads();

    // ---- Phase 2: normalize + MLP, one row per thread (128 rows) ----
    if (tid < 128) {
        const float inv = 1.0f / fmaxf(accb[tid][4], 1e-37f);
        float a[E];
        #pragma unroll
        for (int e = 0; e < E; ++e) a[e] = accb[tid][e] * inv;

        float h1v[H1];
        #pragma unroll
        for (int o = 0; o < H1; ++o) {
            float s = b1[o];
            #pragma unroll
            for (int i = 0; i < E; ++i) s = fmaf(a[i], W1[i * H1 + o], s);
            h1v[o] = fast_tanh(s);
        }
        float h2v[H2];
        #pragma unroll
        for (int o = 0; o < H2; ++o) {
            float s = b2[o];
            #pragma unroll
            for (int i = 0; i < H1; ++i) s = fmaf(h1v[i], W2[i * H2 + o], s);
            h2v[o] = fast_tanh(s);
        }
        float r = b3[0];
        #pragma unroll
        for (int i = 0; i < H2; ++i) r = fmaf(h2v[i], W3[i], r);

        out[(size_t)b * S + qbase + tid] = r;
    }
}

extern "C" void kernel_launch(void* const* d_in, const int* in_sizes, int n_in,
                              void* d_out, int out_size, void* d_ws, size_t ws_size,
                              hipStream_t stream) {
    const float* x  = (const float*)d_in[0];
    const float* Wq = (const float*)d_in[1];
    const float* Wk = (const float*)d_in[2];
    const float* Wv = (const float*)d_in[3];
    const float* W1 = (const float*)d_in[4];
    const float* b1 = (const float*)d_in[5];
    const float* W2 = (const float*)d_in[6];
    const float* b2 = (const float*)d_in[7];
    const float* W3 = (const float*)d_in[8];
    const float* b3 = (const float*)d_in[9];
    float* out = (float*)d_out;

    const int B = in_sizes[0] / (S * E);   // 1024
    attn_mlp_kernel<<<dim3(B * 2), dim3(256), 0, stream>>>(
        x, Wq, Wk, Wv, W1, b1, W2, b2, W3, b3, out);
}

// Round 4
// 89.888 us; speedup vs baseline: 1.0123x; 1.0123x over previous
//
#include <hip/hip_runtime.h>
#include <math.h>

// x [B=1024, S=256, E=4] fp32. One block = one batch (256 threads, 4 waves).
// One-pass softmax, per-row bound m_hat = sqrt(|q|^2 * max|k|^2) in exp2
// domain (m_hat row-uniform -> cross-wave merge is a plain sum).
// Packed hot loop: keys in PAIRS, pair-transposed LDS records, v_pk_fma_f32.
// R11 = revert to best-measured (R7, 88.36 us end-to-end). Session evidence:
// three structurally distinct kernels (this fp32-VALU form; MFMA fp16-split
// R9; MFMA 5-wave/2x-grid R10) all measure 88.4-91.0 us while the rocprof
// top dispatches are the harness's 256 MiB poison fills at 83-85% of HBM
// peak. dur_us is harness-floor-dominated; kernel-side deltas are not
// resolvable. Keeping the best-recorded artifact.
constexpr int S  = 256;
constexpr int E  = 4;
constexpr int H1 = 8;
constexpr int H2 = 4;
constexpr int NW  = 4;        // waves per block
constexpr int NP  = S / 2;    // 128 key pairs
constexpr int PPW = NP / NW;  // 32 pairs per wave
constexpr int R   = 4;        // rows per lane

typedef float v2f __attribute__((ext_vector_type(2)));

__device__ __forceinline__ v2f fma2(v2f a, v2f b, v2f c) {
    return __builtin_elementwise_fma(a, b, c);
}
__device__ __forceinline__ float fast_tanh(float x) {
    const float z = __builtin_amdgcn_exp2f(x * 2.88539008f);  // e^(2x)
    return 1.f - 2.f * __builtin_amdgcn_rcpf(z + 1.f);        // inf-safe
}

__global__ __launch_bounds__(256, 4) void attn_mlp_kernel(
    const float* __restrict__ x,
    const float* __restrict__ Wq, const float* __restrict__ Wk, const float* __restrict__ Wv,
    const float* __restrict__ W1, const float* __restrict__ b1,
    const float* __restrict__ W2, const float* __restrict__ b2,
    const float* __restrict__ W3, const float* __restrict__ b3,
    float* __restrict__ out)
{
    const int b    = blockIdx.x;
    const int tid  = threadIdx.x;
    const int w    = tid >> 6;
    const int lane = tid & 63;

    __shared__ float4 q_lds[S];                       // 4 KB
    __shared__ __align__(16) float kp_lds[NP][E][2];  // 4 KB pair-transposed
    __shared__ __align__(16) float vp_lds[NP][E][2];  // 4 KB
    __shared__ float4 acc_lds[NW][S];                 // 16 KB
    __shared__ float  l_lds[NW][S];                   // 4 KB
    __shared__ float  kmax_lds[NW];

    // ---- Phase 1: q/k/v for row tid; pair-transposed k/v ----
    const float4 xr = *reinterpret_cast<const float4*>(x + ((size_t)b * S + tid) * E);
    const float xv[E] = {xr.x, xr.y, xr.z, xr.w};
    {
        const int jp = tid >> 1, c = tid & 1;
        float4 q;
        float* qp = &q.x;
        float kk = 0.f;
        #pragma unroll
        for (int e = 0; e < E; ++e) {
            float aq = 0.f, ak = 0.f, av = 0.f;
            #pragma unroll
            for (int i = 0; i < E; ++i) {
                aq = fmaf(xv[i], Wq[i * E + e], aq);
                ak = fmaf(xv[i], Wk[i * E + e], ak);
                av = fmaf(xv[i], Wv[i * E + e], av);
            }
            qp[e] = aq * (0.5f * 1.44269504f);  // fold 1/sqrt(E), log2(e)
            kp_lds[jp][e][c] = ak;
            vp_lds[jp][e][c] = av;
            kk = fmaf(ak, ak, kk);
        }
        q_lds[tid] = q;

        #pragma unroll
        for (int off = 32; off > 0; off >>= 1)
            kk = fmaxf(kk, __shfl_xor(kk, off));
        if (lane == 0) kmax_lds[w] = kk;
    }
    __syncthreads();

    const float kmax2 = fmaxf(fmaxf(kmax_lds[0], kmax_lds[1]),
                              fmaxf(kmax_lds[2], kmax_lds[3]));

    // ---- per-lane rows {lane + 64*rr}: splat q and -m_hat into pairs ----
    v2f qx2[R], qy2[R], qz2[R], qw2[R], mh2[R];
    #pragma unroll
    for (int rr = 0; rr < R; ++rr) {
        const float4 q = q_lds[lane + 64 * rr];
        const float qq = fmaf(q.x, q.x, fmaf(q.y, q.y, fmaf(q.z, q.z, q.w * q.w)));
        const float mh = sqrtf(qq * kmax2);  // >= every scaled score
        qx2[rr] = v2f{q.x, q.x};
        qy2[rr] = v2f{q.y, q.y};
        qz2[rr] = v2f{q.z, q.z};
        qw2[rr] = v2f{q.w, q.w};
        mh2[rr] = v2f{-mh, -mh};
    }

    v2f l2[R], a0[R], a1[R], a2[R], a3[R];
    #pragma unroll
    for (int rr = 0; rr < R; ++rr) {
        l2[rr] = v2f{0.f, 0.f};
        a0[rr] = a1[rr] = a2[rr] = a3[rr] = v2f{0.f, 0.f};
    }

    // ---- Phase 2: scan this wave's 32 key pairs (wide b128 reads) ----
    const int p0 = w * PPW;
    #pragma unroll 4
    for (int jp = p0; jp < p0 + PPW; ++jp) {
        const float4* kf = reinterpret_cast<const float4*>(&kp_lds[jp][0][0]);
        const float4* vf = reinterpret_cast<const float4*>(&vp_lds[jp][0][0]);
        const float4 k01 = kf[0], k23 = kf[1];   // ds_read_b128 x2
        const float4 v01 = vf[0], v23 = vf[1];   // ds_read_b128 x2
        const v2f kx = {k01.x, k01.y}, ky = {k01.z, k01.w};
        const v2f kz = {k23.x, k23.y}, kw = {k23.z, k23.w};
        const v2f vx = {v01.x, v01.y}, vy = {v01.z, v01.w};
        const v2f vz = {v23.x, v23.y}, vw = {v23.z, v23.w};
        #pragma unroll
        for (int rr = 0; rr < R; ++rr) {
            v2f s2 = fma2(qw2[rr], kw, mh2[rr]);
            s2 = fma2(qz2[rr], kz, s2);
            s2 = fma2(qy2[rr], ky, s2);
            s2 = fma2(qx2[rr], kx, s2);
            const v2f p2 = {__builtin_amdgcn_exp2f(s2.x),
                            __builtin_amdgcn_exp2f(s2.y)};  // s2 <= 0
            l2[rr] += p2;
            a0[rr] = fma2(p2, vx, a0[rr]);
            a1[rr] = fma2(p2, vy, a1[rr]);
            a2[rr] = fma2(p2, vz, a2[rr]);
            a3[rr] = fma2(p2, vw, a3[rr]);
        }
    }

    // ---- merge partials: plain per-wave stores, no atomics ----
    #pragma unroll
    for (int rr = 0; rr < R; ++rr) {
        const int row = lane + 64 * rr;
        acc_lds[w][row] = make_float4(a0[rr].x + a0[rr].y,
                                      a1[rr].x + a1[rr].y,
                                      a2[rr].x + a2[rr].y,
                                      a3[rr].x + a3[rr].y);
        l_lds[w][row] = l2[rr].x + l2[rr].y;
    }
    __syncthreads();

    // ---- Phase 3: plain-sum merge for row tid, then MLP ----
    float lsum = 0.f;
    float ax = 0.f, ay = 0.f, az = 0.f, aw = 0.f;
    #pragma unroll
    for (int ww = 0; ww < NW; ++ww) {
        lsum += l_lds[ww][tid];
        const float4 a4 = acc_lds[ww][tid];
        ax += a4.x; ay += a4.y; az += a4.z; aw += a4.w;
    }
    const float inv = 1.0f / lsum;
    const float a[E] = {ax * inv, ay * inv, az * inv, aw * inv};

    float h1[H1];
    #pragma unroll
    for (int o = 0; o < H1; ++o) {
        float s = b1[o];
        #pragma unroll
        for (int i = 0; i < E; ++i) s = fmaf(a[i], W1[i * H1 + o], s);
        h1[o] = fast_tanh(s);
    }
    float h2[H2];
    #pragma unroll
    for (int o = 0; o < H2; ++o) {
        float s = b2[o];
        #pragma unroll
        for (int i = 0; i < H1; ++i) s = fmaf(h1[i], W2[i * H2 + o], s);
        h2[o] = fast_tanh(s);
    }
    float r = b3[0];
    #pragma unroll
    for (int i = 0; i < H2; ++i) r = fmaf(h2[i], W3[i], r);

    out[(size_t)b * S + tid] = r;
}

extern "C" void kernel_launch(void* const* d_in, const int* in_sizes, int n_in,
                              void* d_out, int out_size, void* d_ws, size_t ws_size,
                              hipStream_t stream) {
    const float* x  = (const float*)d_in[0];
    const float* Wq = (const float*)d_in[1];
    const float* Wk = (const float*)d_in[2];
    const float* Wv = (const float*)d_in[3];
    const float* W1 = (const float*)d_in[4];
    const float* b1 = (const float*)d_in[5];
    const float* W2 = (const float*)d_in[6];
    const float* b2 = (const float*)d_in[7];
    const float* W3 = (const float*)d_in[8];
    const float* b3 = (const float*)d_in[9];
    float* out = (float*)d_out;

    const int B = in_sizes[0] / (S * E);   // 1024
    attn_mlp_kernel<<<dim3(B), dim3(256), 0, stream>>>(
        x, Wq, Wk, Wv, W1, b1, W2, b2, W3, b3, out);
}